// Round 14
// baseline (905.785 us; speedup 1.0000x reference)
//
#include <hip/hip_runtime.h>
#include <stdint.h>

#define RES 512
#define RANK 48
#define OUT_CH 32
#define KBITS 5
#define NBKT (1 << (3 * KBITS))   // 32768 buckets
#define STR 32                    // padded: 32 u32 (64 bf16 slots) per texel = 128 B = 1 line

typedef unsigned int u32;
typedef unsigned short u16;
typedef u32 u32x4 __attribute__((ext_vector_type(4)));

// ---------- helpers ----------

static __device__ __forceinline__ u16 f2bf(float f){
  u32 u = __float_as_uint(f);
  u32 r = (u + 0x7fffu + ((u >> 16) & 1u)) >> 16;   // RNE, inputs finite
  return (u16)r;
}

static __device__ __forceinline__ void axis_setup(float c, int& o, float& w){
  float f = (c + 1.f) * 255.5f;        // (c+1)*0.5*(RES-1)
  float of = fminf(fmaxf(floorf(f), 0.f), 510.f);
  o = (int)of; w = f - of;
}

static __device__ __forceinline__ void contract(const float* __restrict__ aabb,
                                                float px, float py, float pz,
                                                float& cx, float& cy, float& cz){
  float c0 = (aabb[0] + aabb[3]) * 0.5f;
  float c1 = (aabb[1] + aabb[4]) * 0.5f;
  float c2 = (aabb[2] + aabb[5]) * 0.5f;
  float h0 = fmaxf((aabb[3] - aabb[0]) * 0.5f, 1e-6f);
  float h1 = fmaxf((aabb[4] - aabb[1]) * 0.5f, 1e-6f);
  float h2 = fmaxf((aabb[5] - aabb[2]) * 0.5f, 1e-6f);
  float x0 = (px - c0) / h0;
  float x1 = (py - c1) / h1;
  float x2 = (pz - c2) / h2;
  float linf = fmaxf(fabsf(x0), fmaxf(fabsf(x1), fabsf(x2)));
  float scale = 1.f;
  if (linf > 1.f){ float inv = 1.f / linf; scale = (2.f - inv) * inv; }
  cx = fminf(fmaxf(x0 * scale, -1.f), 1.f);
  cy = fminf(fmaxf(x1 * scale, -1.f), 1.f);
  cz = fminf(fmaxf(x2 * scale, -1.f), 1.f);
}

static __device__ __forceinline__ u32 spread3(u32 x){
  x &= 0x3FF;
  x = (x | (x << 16)) & 0x030000FF;
  x = (x | (x <<  8)) & 0x0300F00F;
  x = (x | (x <<  4)) & 0x030C30C3;
  x = (x | (x <<  2)) & 0x09249249;
  return x;
}

static __device__ __forceinline__ u32 morton_key(float cx, float cy, float cz){
  u32 kx = (u32)fminf(fmaxf((cx + 1.f) * 16.f, 0.f), 31.f);
  u32 ky = (u32)fminf(fmaxf((cy + 1.f) * 16.f, 0.f), 31.f);
  u32 kz = (u32)fminf(fmaxf((cz + 1.f) * 16.f, 0.f), 31.f);
  return spread3(kx) | (spread3(ky) << 1) | (spread3(kz) << 2);   // 15 bits
}

// ---------- zero hist ----------

__global__ void zero_hist(u32* __restrict__ hist)
{
  hist[blockIdx.x * 1024 + threadIdx.x] = 0u;
}

// ---------- fused prep: transpose planes+lines (STR=32 pad) AND hist+keyrank(+staged) ----------

#define TRANS_P 3072
#define TRANS_L 6

template<bool STAGE>
__global__ void prep_fused(const float* __restrict__ pxy, const float* __restrict__ pxz,
                           const float* __restrict__ pyz,
                           const float* __restrict__ lz, const float* __restrict__ ly,
                           const float* __restrict__ lx,
                           const float* __restrict__ coords, const float* __restrict__ aabb,
                           u32* __restrict__ dstP, u32* __restrict__ dstL,
                           u32* __restrict__ hist, u32* __restrict__ keyrank,
                           float4* __restrict__ staged, int n)
{
  __shared__ u32 lds[256 * 25];
  int bid = blockIdx.x;
  int tid = threadIdx.x;
  if (bid < TRANS_P){
    int xh = bid & 1, y = (bid >> 1) & 511, p = bid >> 10;
    const float* src = (p == 0) ? pxy : (p == 1) ? pxz : pyz;
    int x = xh * 256 + tid;
    #pragma unroll
    for (int r2 = 0; r2 < 24; ++r2){
      float f0 = src[((size_t)(2 * r2) * RES + y) * RES + x];
      float f1 = src[((size_t)(2 * r2 + 1) * RES + y) * RES + x];
      lds[tid * 25 + r2] = (u32)f2bf(f0) | ((u32)f2bf(f1) << 16);
    }
    __syncthreads();
    u32* dplane = dstP + (size_t)p * (RES * RES * STR);
    size_t base = ((size_t)y * RES + xh * 256) * STR;
    for (int t = tid; t < 256 * STR; t += 256){
      int tex = t >> 5, r = t & 31;
      dplane[base + t] = (r < 24) ? lds[tex * 25 + r] : 0u;
    }
  } else if (bid < TRANS_P + TRANS_L){
    int g = (bid - TRANS_P) * 256 + tid;
    if (g < 3 * RES){
      int p = g >> 9, i = g & 511;
      const float* src = (p == 0) ? lz : (p == 1) ? ly : lx;
      u32* d = dstL + (size_t)g * STR;
      #pragma unroll
      for (int r2 = 0; r2 < 24; ++r2){
        float f0 = src[(2 * r2) * RES + i];
        float f1 = src[(2 * r2 + 1) * RES + i];
        d[r2] = (u32)f2bf(f0) | ((u32)f2bf(f1) << 16);
      }
      #pragma unroll
      for (int r2 = 24; r2 < STR; ++r2) d[r2] = 0u;
    }
  } else {
    int i = (bid - TRANS_P - TRANS_L) * 256 + tid;
    if (i < n){
      float cx, cy, cz;
      contract(aabb, coords[3*i], coords[3*i+1], coords[3*i+2], cx, cy, cz);
      u32 key = morton_key(cx, cy, cz);
      u32 rank = atomicAdd(hist + key, 1u);
      keyrank[i] = (rank << 15) | key;   // rank < 2^17 (avg ~30/bucket)
      if (STAGE) staged[i] = make_float4(cx, cy, cz, __uint_as_float((u32)i));
    }
  }
}

// ---------- 2-level scan: 32 blocks x 1024 buckets, then tiny top prefix ----------

__global__ void scan_blocks(u32* __restrict__ hist, u32* __restrict__ tops)
{
  __shared__ u32 part[1024];
  int tid = threadIdx.x;
  int idx = blockIdx.x * 1024 + tid;
  u32 v = hist[idx];
  part[tid] = v;
  __syncthreads();
  for (int off = 1; off < 1024; off <<= 1){
    u32 t = 0;
    if (tid >= off) t = part[tid - off];
    __syncthreads();
    part[tid] += t;
    __syncthreads();
  }
  hist[idx] = part[tid] - v;                       // exclusive prefix within chunk
  if (tid == 1023) tops[blockIdx.x] = part[tid];   // chunk total
}

__global__ void scan_tops(u32* __restrict__ tops)
{
  // one thread: exclusive prefix over 32 chunk totals (trivial)
  if (threadIdx.x == 0 && blockIdx.x == 0){
    u32 run = 0;
    #pragma unroll
    for (int b = 0; b < NBKT / 1024; b++){ u32 t = tops[b]; tops[b] = run; run += t; }
  }
}

// ---------- scatter (staged): pure permutation, no recompute ----------

__global__ void key_scatter_staged(const u32* __restrict__ hist, const u32* __restrict__ tops,
                                   const u32* __restrict__ keyrank,
                                   const float4* __restrict__ staged, float4* __restrict__ sorted, int n)
{
  int i = blockIdx.x * 256 + threadIdx.x;
  if (i >= n) return;
  u32 kr = keyrank[i];
  u32 key = kr & 0x7FFFu;
  u32 pos = tops[key >> 10] + hist[key] + (kr >> 15);
  sorted[pos] = staged[i];
}

// ---------- scatter (recompute fallback) ----------

__global__ void key_scatter(const float* __restrict__ coords, const float* __restrict__ aabb,
                            const u32* __restrict__ hist, const u32* __restrict__ tops,
                            const u32* __restrict__ keyrank, float4* __restrict__ sorted, int n)
{
  int i = blockIdx.x * 256 + threadIdx.x;
  if (i >= n) return;
  float cx, cy, cz;
  contract(aabb, coords[3*i], coords[3*i+1], coords[3*i+2], cx, cy, cz);
  u32 kr = keyrank[i];
  u32 key = kr & 0x7FFFu;
  u32 pos = tops[key >> 10] + hist[key] + (kr >> 15);
  sorted[pos] = make_float4(cx, cy, cz, __uint_as_float((u32)i));
}

// ---------- cooperative main kernel: 8 lanes per point (R11 scalar core) ----------
// Lane k of a group owns ranks 8k..8k+7 (u32s 4k..4k+3 of each 128B texel).
// Gather: every texel = ONE u32x4 instr per group (one cache line).
// Matvec: thread (g,k) computes channels 4k..4k+3 of point g over all 48 ranks.

#define EXLO(u) __uint_as_float((u) << 16)
#define EXHI(u) __uint_as_float((u) & 0xffff0000u)

#define CORN_INIT(ps, taddr, wc) \
  { u32x4 _t = *(const u32x4*)(taddr); \
    _Pragma("unroll") for (int c = 0; c < 4; c++){ \
      ps[2*c] = EXLO(_t[c]) * (wc); ps[2*c+1] = EXHI(_t[c]) * (wc); } }

#define CORN_ACC(ps, taddr, wc) \
  { u32x4 _t = *(const u32x4*)(taddr); \
    _Pragma("unroll") for (int c = 0; c < 4; c++){ \
      ps[2*c] = fmaf(EXLO(_t[c]), (wc), ps[2*c]); ps[2*c+1] = fmaf(EXHI(_t[c]), (wc), ps[2*c+1]); } }

// VGPR=48 measured without bounds; 8 waves/EU caps VGPR at 64 (no spill) and
// allows 8 blocks/CU (LDS 15.4KB x 8 = 123KB < 160KB) -> latency hiding.
template<bool SORTED>
__global__ __launch_bounds__(256, 8)
void geo_coop(const float4* __restrict__ sorted,
              const float* __restrict__ coords, const float* __restrict__ aabb,
              const u32* __restrict__ pl, const u32* __restrict__ ln,
              const float* __restrict__ W, const float* __restrict__ bias,
              float* __restrict__ out, int n, int nwg)
{
  // Wlds[k][r] = float4 of W channels 4k..4k+3 at rank r; row stride 49 (bank-rotate)
  __shared__ __align__(16) float Wlds[8 * 49 * 4];    // 6272 B
  __shared__ __align__(16) float vmlds[32][68];       // 8704 B (64 data + 4 pad)

  for (int e = threadIdx.x; e < 8 * RANK * 4; e += 256){
    int k = e / (RANK * 4);
    int rem = e - k * (RANK * 4);
    int r = rem >> 2, j = rem & 3;
    Wlds[(k * 49 + r) * 4 + j] = W[(4 * k + j) * RANK + r];
  }
  __syncthreads();

  int bid = blockIdx.x;
  int swz;
  if (SORTED){
    int q = nwg >> 3, r8 = nwg & 7;
    int xcd = bid & 7, sub = bid >> 3;
    swz = (xcd < r8 ? xcd * (q + 1) : r8 * (q + 1) + (xcd - r8) * q) + sub;
  } else {
    swz = bid;
  }

  int g = threadIdx.x >> 3;   // point slot 0..31
  int k = threadIdx.x & 7;    // lane-in-group (rank slice / channel slice)
  int i = swz * 32 + g;
  bool valid = i < n;
  int ic = valid ? i : (n - 1);

  float cx, cy, cz; u32 oidx;
  if (SORTED){
    u32x4 pr = __builtin_nontemporal_load((const u32x4*)(sorted + ic));
    cx = __uint_as_float(pr[0]);
    cy = __uint_as_float(pr[1]);
    cz = __uint_as_float(pr[2]);
    oidx = pr[3];
  } else {
    contract(aabb, coords[3*ic], coords[3*ic+1], coords[3*ic+2], cx, cy, cz);
    oidx = (u32)ic;
  }

  int ox, oy, oz; float wx, wy, wz;
  axis_setup(cx, ox, wx); axis_setup(cy, oy, wy); axis_setup(cz, oz, wz);
  float uxw = 1.f - wx, uyw = 1.f - wy, uzw = 1.f - wz;

  const u32* A   = pl + ((size_t)oy * RES + ox) * STR + 4 * k;                                // plane_xy
  const u32* B   = pl + (size_t)RES * RES * STR     + ((size_t)oz * RES + ox) * STR + 4 * k;  // plane_xz
  const u32* C   = pl + (size_t)2 * RES * RES * STR + ((size_t)oz * RES + oy) * STR + 4 * k;  // plane_yz
  const u32* LZp = ln +                          (size_t)oz * STR + 4 * k;
  const u32* LYp = ln + (size_t)RES * STR     + (size_t)oy * STR + 4 * k;
  const u32* LXp = ln + (size_t)2 * RES * STR + (size_t)ox * STR + 4 * k;

  float vm8[8];
  #pragma unroll
  for (int j = 0; j < 8; j++) vm8[j] = 0.f;

  // plane_xy * line_z
  {
    u32x4 l0 = *(const u32x4*)(LZp);
    u32x4 l1 = *(const u32x4*)(LZp + STR);
    float lv8[8], ps8[8];
    #pragma unroll
    for (int c = 0; c < 4; c++){
      float a0 = EXLO(l0[c]), a1 = EXHI(l0[c]);
      float b0 = EXLO(l1[c]), b1 = EXHI(l1[c]);
      lv8[2*c]   = fmaf(wz, b0 - a0, a0);
      lv8[2*c+1] = fmaf(wz, b1 - a1, a1);
    }
    CORN_INIT(ps8, A,                 uyw * uxw);
    CORN_ACC (ps8, A + STR,           uyw * wx);
    CORN_ACC (ps8, A + RES * STR,     wy * uxw);
    CORN_ACC (ps8, A + RES * STR + STR, wy * wx);
    #pragma unroll
    for (int j = 0; j < 8; j++) vm8[j] = fmaf(ps8[j], lv8[j], vm8[j]);
  }
  // plane_xz * line_y
  {
    u32x4 l0 = *(const u32x4*)(LYp);
    u32x4 l1 = *(const u32x4*)(LYp + STR);
    float lv8[8], ps8[8];
    #pragma unroll
    for (int c = 0; c < 4; c++){
      float a0 = EXLO(l0[c]), a1 = EXHI(l0[c]);
      float b0 = EXLO(l1[c]), b1 = EXHI(l1[c]);
      lv8[2*c]   = fmaf(wy, b0 - a0, a0);
      lv8[2*c+1] = fmaf(wy, b1 - a1, a1);
    }
    CORN_INIT(ps8, B,                 uzw * uxw);
    CORN_ACC (ps8, B + STR,           uzw * wx);
    CORN_ACC (ps8, B + RES * STR,     wz * uxw);
    CORN_ACC (ps8, B + RES * STR + STR, wz * wx);
    #pragma unroll
    for (int j = 0; j < 8; j++) vm8[j] = fmaf(ps8[j], lv8[j], vm8[j]);
  }
  // plane_yz * line_x
  {
    u32x4 l0 = *(const u32x4*)(LXp);
    u32x4 l1 = *(const u32x4*)(LXp + STR);
    float lv8[8], ps8[8];
    #pragma unroll
    for (int c = 0; c < 4; c++){
      float a0 = EXLO(l0[c]), a1 = EXHI(l0[c]);
      float b0 = EXLO(l1[c]), b1 = EXHI(l1[c]);
      lv8[2*c]   = fmaf(wx, b0 - a0, a0);
      lv8[2*c+1] = fmaf(wx, b1 - a1, a1);
    }
    CORN_INIT(ps8, C,                 uzw * uyw);
    CORN_ACC (ps8, C + STR,           uzw * wy);
    CORN_ACC (ps8, C + RES * STR,     wz * uyw);
    CORN_ACC (ps8, C + RES * STR + STR, wz * wy);
    #pragma unroll
    for (int j = 0; j < 8; j++) vm8[j] = fmaf(ps8[j], lv8[j], vm8[j]);
  }

  // hand off vm to LDS (f32, exact)
  *(float4*)&vmlds[g][8 * k]     = make_float4(vm8[0], vm8[1], vm8[2], vm8[3]);
  *(float4*)&vmlds[g][8 * k + 4] = make_float4(vm8[4], vm8[5], vm8[6], vm8[7]);
  __syncthreads();

  // matvec: thread (g,k) -> channels 4k..4k+3 of point g over all 48 ranks
  float vmv[RANK];
  #pragma unroll
  for (int qd = 0; qd < 12; qd++){
    float4 v4 = *(const float4*)&vmlds[g][qd * 4];
    vmv[4*qd+0] = v4.x; vmv[4*qd+1] = v4.y; vmv[4*qd+2] = v4.z; vmv[4*qd+3] = v4.w;
  }
  float4 accv = ((const float4*)bias)[k];
  const float4* wk = (const float4*)(Wlds + (size_t)k * 49 * 4);
  #pragma unroll
  for (int r = 0; r < RANK; r++){
    float4 w4 = wk[r];
    accv.x = fmaf(vmv[r], w4.x, accv.x);
    accv.y = fmaf(vmv[r], w4.y, accv.y);
    accv.z = fmaf(vmv[r], w4.z, accv.z);
    accv.w = fmaf(vmv[r], w4.w, accv.w);
  }

  if (valid){
    *(float4*)(out + (size_t)oidx * 32 + 4 * k) = accv;
  }
}

// ---------- fallback (ws too small): direct sampling from original layout ----------

__global__ __launch_bounds__(256, 2)
void geo_direct(const float* __restrict__ coords, const float* __restrict__ aabb,
                const float* __restrict__ PXY, const float* __restrict__ PXZ, const float* __restrict__ PYZ,
                const float* __restrict__ LZ, const float* __restrict__ LY, const float* __restrict__ LX,
                const float* __restrict__ W, const float* __restrict__ bias,
                float* __restrict__ out, int n)
{
  __shared__ __align__(16) float Wt[RANK * OUT_CH];
  for (int t = threadIdx.x; t < RANK * OUT_CH; t += 256){
    int r = t >> 5, o = t & 31;
    Wt[t] = W[o * RANK + r];
  }
  __syncthreads();

  int i = blockIdx.x * 256 + threadIdx.x;
  if (i >= n) return;

  float cx, cy, cz;
  contract(aabb, coords[3*i], coords[3*i+1], coords[3*i+2], cx, cy, cz);
  int ox, oy, oz; float wx, wy, wz;
  axis_setup(cx, ox, wx); axis_setup(cy, oy, wy); axis_setup(cz, oz, wz);

  int offA = oy * RES + ox, offB = oz * RES + ox, offC = oz * RES + oy;
  float uxw = 1.f - wx, uyw = 1.f - wy, uzw = 1.f - wz;
  float aw00 = uyw*uxw, aw01 = uyw*wx, aw10 = wy*uxw, aw11 = wy*wx;
  float bw00 = uzw*uxw, bw01 = uzw*wx, bw10 = wz*uxw, bw11 = wz*wx;
  float cw00 = uzw*uyw, cw01 = uzw*wy, cw10 = wz*uyw, cw11 = wz*wy;

  float acc[OUT_CH];
  #pragma unroll
  for (int o = 0; o < 8; o++){
    float4 bv = *(const float4*)(bias + o * 4);
    acc[4*o+0] = bv.x; acc[4*o+1] = bv.y; acc[4*o+2] = bv.z; acc[4*o+3] = bv.w;
  }
  const float4* Wt4 = (const float4*)Wt;

  for (int r = 0; r < RANK; r++){
    const float* pA = PXY + (size_t)r * RES * RES;
    const float* pB = PXZ + (size_t)r * RES * RES;
    const float* pC = PYZ + (size_t)r * RES * RES;
    float va = fmaf(pA[offA], aw00, fmaf(pA[offA+1], aw01, fmaf(pA[offA+RES], aw10, pA[offA+RES+1]*aw11)));
    float vb = fmaf(pB[offB], bw00, fmaf(pB[offB+1], bw01, fmaf(pB[offB+RES], bw10, pB[offB+RES+1]*bw11)));
    float vc = fmaf(pC[offC], cw00, fmaf(pC[offC+1], cw01, fmaf(pC[offC+RES], cw10, pC[offC+RES+1]*cw11)));
    float l0;
    l0 = LZ[r * RES + oz];
    float lzv = fmaf(wz, LZ[r * RES + oz + 1] - l0, l0);
    l0 = LY[r * RES + oy];
    float lyv = fmaf(wy, LY[r * RES + oy + 1] - l0, l0);
    l0 = LX[r * RES + ox];
    float lxv = fmaf(wx, LX[r * RES + ox + 1] - l0, l0);
    float vm = fmaf(va, lzv, fmaf(vb, lyv, vc * lxv));
    const float4* wrow = Wt4 + r * 8;
    #pragma unroll
    for (int q = 0; q < 8; q++){
      float4 w4 = wrow[q];
      acc[4*q+0] = fmaf(vm, w4.x, acc[4*q+0]); acc[4*q+1] = fmaf(vm, w4.y, acc[4*q+1]);
      acc[4*q+2] = fmaf(vm, w4.z, acc[4*q+2]); acc[4*q+3] = fmaf(vm, w4.w, acc[4*q+3]);
    }
  }

  float4* o4 = (float4*)(out + (size_t)i * 32);
  #pragma unroll
  for (int q = 0; q < 8; q++)
    o4[q] = make_float4(acc[4*q+0], acc[4*q+1], acc[4*q+2], acc[4*q+3]);
}

// ---------- launch ----------

extern "C" void kernel_launch(void* const* d_in, const int* in_sizes, int n_in,
                              void* d_out, int out_size, void* d_ws, size_t ws_size,
                              hipStream_t stream)
{
  const float* coords = (const float*)d_in[0];
  const float* aabb   = (const float*)d_in[1];
  const float* pxy    = (const float*)d_in[2];
  const float* pxz    = (const float*)d_in[3];
  const float* pyz    = (const float*)d_in[4];
  const float* lz     = (const float*)d_in[5];
  const float* ly     = (const float*)d_in[6];
  const float* lx     = (const float*)d_in[7];
  const float* W      = (const float*)d_in[8];
  const float* bias   = (const float*)d_in[9];
  float* out = (float*)d_out;
  int n = in_sizes[0] / 3;
  int nwg256 = (n + 255) / 256;
  int nwg32  = (n + 31) / 32;

  const size_t planesU = (size_t)3 * RES * RES * STR;   // padded
  const size_t linesU  = (size_t)3 * RES * STR;
  const size_t histU   = NBKT;
  const size_t topsU   = 64;
  const size_t keyrU   = (size_t)n;
  const size_t sortedU = (size_t)4 * n;
  const size_t stagedU = (size_t)4 * n;
  const size_t needStaged = (planesU + linesU + histU + topsU + keyrU + sortedU + stagedU) * 4;
  const size_t needFull   = (planesU + linesU + histU + topsU + keyrU + sortedU) * 4;

  if (ws_size >= needStaged){
    u32* pl      = (u32*)d_ws;
    u32* ln      = pl + planesU;
    u32* hist    = ln + linesU;
    u32* tops    = hist + histU;
    u32* keyrank = tops + topsU;
    float4* sorted = (float4*)(keyrank + keyrU);
    float4* staged = sorted + n;
    zero_hist<<<NBKT / 1024, 1024, 0, stream>>>(hist);
    prep_fused<true><<<TRANS_P + TRANS_L + nwg256, 256, 0, stream>>>(
        pxy, pxz, pyz, lz, ly, lx, coords, aabb, pl, ln, hist, keyrank, staged, n);
    scan_blocks<<<NBKT / 1024, 1024, 0, stream>>>(hist, tops);
    scan_tops<<<1, 64, 0, stream>>>(tops);
    key_scatter_staged<<<nwg256, 256, 0, stream>>>(hist, tops, keyrank, staged, sorted, n);
    geo_coop<true><<<nwg32, 256, 0, stream>>>(sorted, nullptr, nullptr, pl, ln, W, bias, out, n, nwg32);
  } else if (ws_size >= needFull){
    u32* pl      = (u32*)d_ws;
    u32* ln      = pl + planesU;
    u32* hist    = ln + linesU;
    u32* tops    = hist + histU;
    u32* keyrank = tops + topsU;
    float4* sorted = (float4*)(keyrank + keyrU);
    zero_hist<<<NBKT / 1024, 1024, 0, stream>>>(hist);
    prep_fused<false><<<TRANS_P + TRANS_L + nwg256, 256, 0, stream>>>(
        pxy, pxz, pyz, lz, ly, lx, coords, aabb, pl, ln, hist, keyrank, nullptr, n);
    scan_blocks<<<NBKT / 1024, 1024, 0, stream>>>(hist, tops);
    scan_tops<<<1, 64, 0, stream>>>(tops);
    key_scatter<<<nwg256, 256, 0, stream>>>(coords, aabb, hist, tops, keyrank, sorted, n);
    geo_coop<true><<<nwg32, 256, 0, stream>>>(sorted, nullptr, nullptr, pl, ln, W, bias, out, n, nwg32);
  } else if (ws_size >= (planesU + linesU) * 4){
    u32* pl = (u32*)d_ws;
    u32* ln = pl + planesU;
    prep_fused<false><<<TRANS_P + TRANS_L, 256, 0, stream>>>(
        pxy, pxz, pyz, lz, ly, lx, coords, aabb, pl, ln, (u32*)pl, (u32*)pl, nullptr, 0);
    geo_coop<false><<<nwg32, 256, 0, stream>>>(nullptr, coords, aabb, pl, ln, W, bias, out, n, nwg32);
  } else {
    geo_direct<<<nwg256, 256, 0, stream>>>(coords, aabb, pxy, pxz, pyz, lz, ly, lx, W, bias, out, n);
  }
}

// Round 15
// 439.455 us; speedup vs baseline: 2.0612x; 2.0612x over previous
//
#include <hip/hip_runtime.h>
#include <stdint.h>

#define RES 512
#define RANK 48
#define OUT_CH 32
#define KBITS 5
#define NBKT (1 << (3 * KBITS))   // 32768 buckets
#define STR 32                    // padded: 32 u32 (64 bf16 slots) per texel = 128 B = 1 line

typedef unsigned int u32;
typedef unsigned short u16;
typedef u32 u32x4 __attribute__((ext_vector_type(4)));

// ---------- helpers ----------

static __device__ __forceinline__ u16 f2bf(float f){
  u32 u = __float_as_uint(f);
  u32 r = (u + 0x7fffu + ((u >> 16) & 1u)) >> 16;   // RNE, inputs finite
  return (u16)r;
}

static __device__ __forceinline__ void axis_setup(float c, int& o, float& w){
  float f = (c + 1.f) * 255.5f;        // (c+1)*0.5*(RES-1)
  float of = fminf(fmaxf(floorf(f), 0.f), 510.f);
  o = (int)of; w = f - of;
}

static __device__ __forceinline__ void contract(const float* __restrict__ aabb,
                                                float px, float py, float pz,
                                                float& cx, float& cy, float& cz){
  float c0 = (aabb[0] + aabb[3]) * 0.5f;
  float c1 = (aabb[1] + aabb[4]) * 0.5f;
  float c2 = (aabb[2] + aabb[5]) * 0.5f;
  float h0 = fmaxf((aabb[3] - aabb[0]) * 0.5f, 1e-6f);
  float h1 = fmaxf((aabb[4] - aabb[1]) * 0.5f, 1e-6f);
  float h2 = fmaxf((aabb[5] - aabb[2]) * 0.5f, 1e-6f);
  float x0 = (px - c0) / h0;
  float x1 = (py - c1) / h1;
  float x2 = (pz - c2) / h2;
  float linf = fmaxf(fabsf(x0), fmaxf(fabsf(x1), fabsf(x2)));
  float scale = 1.f;
  if (linf > 1.f){ float inv = 1.f / linf; scale = (2.f - inv) * inv; }
  cx = fminf(fmaxf(x0 * scale, -1.f), 1.f);
  cy = fminf(fmaxf(x1 * scale, -1.f), 1.f);
  cz = fminf(fmaxf(x2 * scale, -1.f), 1.f);
}

static __device__ __forceinline__ u32 spread3(u32 x){
  x &= 0x3FF;
  x = (x | (x << 16)) & 0x030000FF;
  x = (x | (x <<  8)) & 0x0300F00F;
  x = (x | (x <<  4)) & 0x030C30C3;
  x = (x | (x <<  2)) & 0x09249249;
  return x;
}

static __device__ __forceinline__ u32 morton_key(float cx, float cy, float cz){
  u32 kx = (u32)fminf(fmaxf((cx + 1.f) * 16.f, 0.f), 31.f);
  u32 ky = (u32)fminf(fmaxf((cy + 1.f) * 16.f, 0.f), 31.f);
  u32 kz = (u32)fminf(fmaxf((cz + 1.f) * 16.f, 0.f), 31.f);
  return spread3(kx) | (spread3(ky) << 1) | (spread3(kz) << 2);   // 15 bits
}

// ---------- zero hist ----------

__global__ void zero_hist(u32* __restrict__ hist)
{
  hist[blockIdx.x * 1024 + threadIdx.x] = 0u;
}

// ---------- fused prep: transpose planes+lines+W (STR=32 pad) AND hist+keyrank(+staged) ----------

#define TRANS_P 3072
#define TRANS_L 6

template<bool STAGE>
__global__ void prep_fused(const float* __restrict__ pxy, const float* __restrict__ pxz,
                           const float* __restrict__ pyz,
                           const float* __restrict__ lz, const float* __restrict__ ly,
                           const float* __restrict__ lx,
                           const float* __restrict__ W, float* __restrict__ wt,
                           const float* __restrict__ coords, const float* __restrict__ aabb,
                           u32* __restrict__ dstP, u32* __restrict__ dstL,
                           u32* __restrict__ hist, u32* __restrict__ keyrank,
                           float4* __restrict__ staged, int n)
{
  __shared__ u32 lds[256 * 25];
  int bid = blockIdx.x;
  int tid = threadIdx.x;
  if (bid < TRANS_P){
    int xh = bid & 1, y = (bid >> 1) & 511, p = bid >> 10;
    const float* src = (p == 0) ? pxy : (p == 1) ? pxz : pyz;
    int x = xh * 256 + tid;
    #pragma unroll
    for (int r2 = 0; r2 < 24; ++r2){
      float f0 = src[((size_t)(2 * r2) * RES + y) * RES + x];
      float f1 = src[((size_t)(2 * r2 + 1) * RES + y) * RES + x];
      lds[tid * 25 + r2] = (u32)f2bf(f0) | ((u32)f2bf(f1) << 16);
    }
    __syncthreads();
    u32* dplane = dstP + (size_t)p * (RES * RES * STR);
    size_t base = ((size_t)y * RES + xh * 256) * STR;
    for (int t = tid; t < 256 * STR; t += 256){
      int tex = t >> 5, r = t & 31;
      dplane[base + t] = (r < 24) ? lds[tex * 25 + r] : 0u;
    }
  } else if (bid < TRANS_P + TRANS_L){
    int g = (bid - TRANS_P) * 256 + tid;   // 0..1535 == 3*RES == RANK*OUT_CH
    {
      int p = g >> 9, i = g & 511;
      const float* src = (p == 0) ? lz : (p == 1) ? ly : lx;
      u32* d = dstL + (size_t)g * STR;
      #pragma unroll
      for (int r2 = 0; r2 < 24; ++r2){
        float f0 = src[(2 * r2) * RES + i];
        float f1 = src[(2 * r2 + 1) * RES + i];
        d[r2] = (u32)f2bf(f0) | ((u32)f2bf(f1) << 16);
      }
      #pragma unroll
      for (int r2 = 24; r2 < STR; ++r2) d[r2] = 0u;
    }
    // W^T fill: wt[r*32+o] = W[o*48+r]; g = r*32+o
    wt[g] = W[(g & 31) * RANK + (g >> 5)];
  } else {
    int i = (bid - TRANS_P - TRANS_L) * 256 + tid;
    if (i < n){
      float cx, cy, cz;
      contract(aabb, coords[3*i], coords[3*i+1], coords[3*i+2], cx, cy, cz);
      u32 key = morton_key(cx, cy, cz);
      u32 rank = atomicAdd(hist + key, 1u);
      keyrank[i] = (rank << 15) | key;   // rank < 2^17 (avg ~30/bucket)
      if (STAGE) staged[i] = make_float4(cx, cy, cz, __uint_as_float((u32)i));
    }
  }
}

// ---------- 2-level scan: 32 blocks x 1024 buckets, then tiny top prefix ----------

__global__ void scan_blocks(u32* __restrict__ hist, u32* __restrict__ tops)
{
  __shared__ u32 part[1024];
  int tid = threadIdx.x;
  int idx = blockIdx.x * 1024 + tid;
  u32 v = hist[idx];
  part[tid] = v;
  __syncthreads();
  for (int off = 1; off < 1024; off <<= 1){
    u32 t = 0;
    if (tid >= off) t = part[tid - off];
    __syncthreads();
    part[tid] += t;
    __syncthreads();
  }
  hist[idx] = part[tid] - v;                       // exclusive prefix within chunk
  if (tid == 1023) tops[blockIdx.x] = part[tid];   // chunk total
}

__global__ void scan_tops(u32* __restrict__ tops)
{
  if (threadIdx.x == 0 && blockIdx.x == 0){
    u32 run = 0;
    #pragma unroll
    for (int b = 0; b < NBKT / 1024; b++){ u32 t = tops[b]; tops[b] = run; run += t; }
  }
}

// ---------- scatter (staged): pure permutation, no recompute ----------

__global__ void key_scatter_staged(const u32* __restrict__ hist, const u32* __restrict__ tops,
                                   const u32* __restrict__ keyrank,
                                   const float4* __restrict__ staged, float4* __restrict__ sorted, int n)
{
  int i = blockIdx.x * 256 + threadIdx.x;
  if (i >= n) return;
  u32 kr = keyrank[i];
  u32 key = kr & 0x7FFFu;
  u32 pos = tops[key >> 10] + hist[key] + (kr >> 15);
  sorted[pos] = staged[i];
}

// ---------- scatter (recompute fallback) ----------

__global__ void key_scatter(const float* __restrict__ coords, const float* __restrict__ aabb,
                            const u32* __restrict__ hist, const u32* __restrict__ tops,
                            const u32* __restrict__ keyrank, float4* __restrict__ sorted, int n)
{
  int i = blockIdx.x * 256 + threadIdx.x;
  if (i >= n) return;
  float cx, cy, cz;
  contract(aabb, coords[3*i], coords[3*i+1], coords[3*i+2], cx, cy, cz);
  u32 kr = keyrank[i];
  u32 key = kr & 0x7FFFu;
  u32 pos = tops[key >> 10] + hist[key] + (kr >> 15);
  sorted[pos] = make_float4(cx, cy, cz, __uint_as_float((u32)i));
}

// ---------- cooperative main kernel: 8 lanes per point gather + remapped matvec ----------
// Gather phase: lane k of group g owns ranks 8k..8k+7; each texel = ONE u32x4.
// Matvec phase (remapped): wave w, half h, lane&31 = point g -> channels 4*(2w+h)..+3.
// W^T read from global (L1-hot, wave-half-uniform address -> broadcast).

#define EXLO(u) __uint_as_float((u) << 16)
#define EXHI(u) __uint_as_float((u) & 0xffff0000u)

#define CORN_INIT(ps, taddr, wc) \
  { u32x4 _t = *(const u32x4*)(taddr); \
    _Pragma("unroll") for (int c = 0; c < 4; c++){ \
      ps[2*c] = EXLO(_t[c]) * (wc); ps[2*c+1] = EXHI(_t[c]) * (wc); } }

#define CORN_ACC(ps, taddr, wc) \
  { u32x4 _t = *(const u32x4*)(taddr); \
    _Pragma("unroll") for (int c = 0; c < 4; c++){ \
      ps[2*c] = fmaf(EXLO(_t[c]), (wc), ps[2*c]); ps[2*c+1] = fmaf(EXHI(_t[c]), (wc), ps[2*c+1]); } }

template<bool SORTED>
__global__ __launch_bounds__(256, 2)
void geo_coop(const float4* __restrict__ sorted,
              const float* __restrict__ coords, const float* __restrict__ aabb,
              const u32* __restrict__ pl, const u32* __restrict__ ln,
              const float* __restrict__ Wt, const float* __restrict__ bias,
              float* __restrict__ out, int n, int nwg)
{
  __shared__ __align__(16) float vmlds[32][68];       // 8704 B (64 vm + oidx@64 + pad)

  int bid = blockIdx.x;
  int swz;
  if (SORTED){
    int q = nwg >> 3, r8 = nwg & 7;
    int xcd = bid & 7, sub = bid >> 3;
    swz = (xcd < r8 ? xcd * (q + 1) : r8 * (q + 1) + (xcd - r8) * q) + sub;
  } else {
    swz = bid;
  }

  int g = threadIdx.x >> 3;   // point slot 0..31
  int k = threadIdx.x & 7;    // lane-in-group (rank slice)
  int i = swz * 32 + g;
  bool valid = i < n;
  int ic = valid ? i : (n - 1);

  float cx, cy, cz; u32 oidx;
  if (SORTED){
    u32x4 pr = __builtin_nontemporal_load((const u32x4*)(sorted + ic));
    cx = __uint_as_float(pr[0]);
    cy = __uint_as_float(pr[1]);
    cz = __uint_as_float(pr[2]);
    oidx = pr[3];
  } else {
    contract(aabb, coords[3*ic], coords[3*ic+1], coords[3*ic+2], cx, cy, cz);
    oidx = (u32)ic;
  }

  int ox, oy, oz; float wx, wy, wz;
  axis_setup(cx, ox, wx); axis_setup(cy, oy, wy); axis_setup(cz, oz, wz);
  float uxw = 1.f - wx, uyw = 1.f - wy, uzw = 1.f - wz;

  const u32* A   = pl + ((size_t)oy * RES + ox) * STR + 4 * k;                                // plane_xy
  const u32* B   = pl + (size_t)RES * RES * STR     + ((size_t)oz * RES + ox) * STR + 4 * k;  // plane_xz
  const u32* C   = pl + (size_t)2 * RES * RES * STR + ((size_t)oz * RES + oy) * STR + 4 * k;  // plane_yz
  const u32* LZp = ln +                          (size_t)oz * STR + 4 * k;
  const u32* LYp = ln + (size_t)RES * STR     + (size_t)oy * STR + 4 * k;
  const u32* LXp = ln + (size_t)2 * RES * STR + (size_t)ox * STR + 4 * k;

  float vm8[8];
  #pragma unroll
  for (int j = 0; j < 8; j++) vm8[j] = 0.f;

  // plane_xy * line_z
  {
    u32x4 l0 = *(const u32x4*)(LZp);
    u32x4 l1 = *(const u32x4*)(LZp + STR);
    float lv8[8], ps8[8];
    #pragma unroll
    for (int c = 0; c < 4; c++){
      float a0 = EXLO(l0[c]), a1 = EXHI(l0[c]);
      float b0 = EXLO(l1[c]), b1 = EXHI(l1[c]);
      lv8[2*c]   = fmaf(wz, b0 - a0, a0);
      lv8[2*c+1] = fmaf(wz, b1 - a1, a1);
    }
    CORN_INIT(ps8, A,                 uyw * uxw);
    CORN_ACC (ps8, A + STR,           uyw * wx);
    CORN_ACC (ps8, A + RES * STR,     wy * uxw);
    CORN_ACC (ps8, A + RES * STR + STR, wy * wx);
    #pragma unroll
    for (int j = 0; j < 8; j++) vm8[j] = fmaf(ps8[j], lv8[j], vm8[j]);
  }
  // plane_xz * line_y
  {
    u32x4 l0 = *(const u32x4*)(LYp);
    u32x4 l1 = *(const u32x4*)(LYp + STR);
    float lv8[8], ps8[8];
    #pragma unroll
    for (int c = 0; c < 4; c++){
      float a0 = EXLO(l0[c]), a1 = EXHI(l0[c]);
      float b0 = EXLO(l1[c]), b1 = EXHI(l1[c]);
      lv8[2*c]   = fmaf(wy, b0 - a0, a0);
      lv8[2*c+1] = fmaf(wy, b1 - a1, a1);
    }
    CORN_INIT(ps8, B,                 uzw * uxw);
    CORN_ACC (ps8, B + STR,           uzw * wx);
    CORN_ACC (ps8, B + RES * STR,     wz * uxw);
    CORN_ACC (ps8, B + RES * STR + STR, wz * wx);
    #pragma unroll
    for (int j = 0; j < 8; j++) vm8[j] = fmaf(ps8[j], lv8[j], vm8[j]);
  }
  // plane_yz * line_x
  {
    u32x4 l0 = *(const u32x4*)(LXp);
    u32x4 l1 = *(const u32x4*)(LXp + STR);
    float lv8[8], ps8[8];
    #pragma unroll
    for (int c = 0; c < 4; c++){
      float a0 = EXLO(l0[c]), a1 = EXHI(l0[c]);
      float b0 = EXLO(l1[c]), b1 = EXHI(l1[c]);
      lv8[2*c]   = fmaf(wx, b0 - a0, a0);
      lv8[2*c+1] = fmaf(wx, b1 - a1, a1);
    }
    CORN_INIT(ps8, C,                 uzw * uyw);
    CORN_ACC (ps8, C + STR,           uzw * wy);
    CORN_ACC (ps8, C + RES * STR,     wz * uyw);
    CORN_ACC (ps8, C + RES * STR + STR, wz * wy);
    #pragma unroll
    for (int j = 0; j < 8; j++) vm8[j] = fmaf(ps8[j], lv8[j], vm8[j]);
  }

  // hand off vm (f32, exact) + oidx to LDS
  *(float4*)&vmlds[g][8 * k]     = make_float4(vm8[0], vm8[1], vm8[2], vm8[3]);
  *(float4*)&vmlds[g][8 * k + 4] = make_float4(vm8[4], vm8[5], vm8[6], vm8[7]);
  if (k == 0) vmlds[g][64] = __uint_as_float(oidx);
  __syncthreads();

  // ---- remapped matvec: wave w, half h, point g2=lane&31 -> channels 4*(2w+h)..+3 ----
  int w  = threadIdx.x >> 6;
  int l  = threadIdx.x & 63;
  int g2 = l & 31;
  int h  = l >> 5;
  int c4 = 2 * w + h;          // float4-channel index 0..7 (uniform per wave-half)

  float vmv[RANK];
  #pragma unroll
  for (int qd = 0; qd < 12; qd++){
    float4 v4 = *(const float4*)&vmlds[g2][qd * 4];
    vmv[4*qd+0] = v4.x; vmv[4*qd+1] = v4.y; vmv[4*qd+2] = v4.z; vmv[4*qd+3] = v4.w;
  }
  u32 oidx2 = __float_as_uint(vmlds[g2][64]);
  bool valid2 = (swz * 32 + g2) < n;

  float4 accv = ((const float4*)bias)[c4];
  const float4* wt4 = (const float4*)Wt;   // Wt[r*32+o] -> float4 idx r*8 + c4
  #pragma unroll
  for (int r = 0; r < RANK; r++){
    float4 w4 = wt4[r * 8 + c4];
    accv.x = fmaf(vmv[r], w4.x, accv.x);
    accv.y = fmaf(vmv[r], w4.y, accv.y);
    accv.z = fmaf(vmv[r], w4.z, accv.z);
    accv.w = fmaf(vmv[r], w4.w, accv.w);
  }

  if (valid2){
    *(float4*)(out + (size_t)oidx2 * 32 + 4 * c4) = accv;
  }
}

// ---------- fallback (ws too small): direct sampling from original layout ----------

__global__ __launch_bounds__(256, 2)
void geo_direct(const float* __restrict__ coords, const float* __restrict__ aabb,
                const float* __restrict__ PXY, const float* __restrict__ PXZ, const float* __restrict__ PYZ,
                const float* __restrict__ LZ, const float* __restrict__ LY, const float* __restrict__ LX,
                const float* __restrict__ W, const float* __restrict__ bias,
                float* __restrict__ out, int n)
{
  __shared__ __align__(16) float Wt[RANK * OUT_CH];
  for (int t = threadIdx.x; t < RANK * OUT_CH; t += 256){
    int r = t >> 5, o = t & 31;
    Wt[t] = W[o * RANK + r];
  }
  __syncthreads();

  int i = blockIdx.x * 256 + threadIdx.x;
  if (i >= n) return;

  float cx, cy, cz;
  contract(aabb, coords[3*i], coords[3*i+1], coords[3*i+2], cx, cy, cz);
  int ox, oy, oz; float wx, wy, wz;
  axis_setup(cx, ox, wx); axis_setup(cy, oy, wy); axis_setup(cz, oz, wz);

  int offA = oy * RES + ox, offB = oz * RES + ox, offC = oz * RES + oy;
  float uxw = 1.f - wx, uyw = 1.f - wy, uzw = 1.f - wz;
  float aw00 = uyw*uxw, aw01 = uyw*wx, aw10 = wy*uxw, aw11 = wy*wx;
  float bw00 = uzw*uxw, bw01 = uzw*wx, bw10 = wz*uxw, bw11 = wz*wx;
  float cw00 = uzw*uyw, cw01 = uzw*wy, cw10 = wz*uyw, cw11 = wz*wy;

  float acc[OUT_CH];
  #pragma unroll
  for (int o = 0; o < 8; o++){
    float4 bv = *(const float4*)(bias + o * 4);
    acc[4*o+0] = bv.x; acc[4*o+1] = bv.y; acc[4*o+2] = bv.z; acc[4*o+3] = bv.w;
  }
  const float4* Wt4 = (const float4*)Wt;

  for (int r = 0; r < RANK; r++){
    const float* pA = PXY + (size_t)r * RES * RES;
    const float* pB = PXZ + (size_t)r * RES * RES;
    const float* pC = PYZ + (size_t)r * RES * RES;
    float va = fmaf(pA[offA], aw00, fmaf(pA[offA+1], aw01, fmaf(pA[offA+RES], aw10, pA[offA+RES+1]*aw11)));
    float vb = fmaf(pB[offB], bw00, fmaf(pB[offB+1], bw01, fmaf(pB[offB+RES], bw10, pB[offB+RES+1]*bw11)));
    float vc = fmaf(pC[offC], cw00, fmaf(pC[offC+1], cw01, fmaf(pC[offC+RES], cw10, pC[offC+RES+1]*cw11)));
    float l0;
    l0 = LZ[r * RES + oz];
    float lzv = fmaf(wz, LZ[r * RES + oz + 1] - l0, l0);
    l0 = LY[r * RES + oy];
    float lyv = fmaf(wy, LY[r * RES + oy + 1] - l0, l0);
    l0 = LX[r * RES + ox];
    float lxv = fmaf(wx, LX[r * RES + ox + 1] - l0, l0);
    float vm = fmaf(va, lzv, fmaf(vb, lyv, vc * lxv));
    const float4* wrow = Wt4 + r * 8;
    #pragma unroll
    for (int q = 0; q < 8; q++){
      float4 w4 = wrow[q];
      acc[4*q+0] = fmaf(vm, w4.x, acc[4*q+0]); acc[4*q+1] = fmaf(vm, w4.y, acc[4*q+1]);
      acc[4*q+2] = fmaf(vm, w4.z, acc[4*q+2]); acc[4*q+3] = fmaf(vm, w4.w, acc[4*q+3]);
    }
  }

  float4* o4 = (float4*)(out + (size_t)i * 32);
  #pragma unroll
  for (int q = 0; q < 8; q++)
    o4[q] = make_float4(acc[4*q+0], acc[4*q+1], acc[4*q+2], acc[4*q+3]);
}

// ---------- launch ----------

extern "C" void kernel_launch(void* const* d_in, const int* in_sizes, int n_in,
                              void* d_out, int out_size, void* d_ws, size_t ws_size,
                              hipStream_t stream)
{
  const float* coords = (const float*)d_in[0];
  const float* aabb   = (const float*)d_in[1];
  const float* pxy    = (const float*)d_in[2];
  const float* pxz    = (const float*)d_in[3];
  const float* pyz    = (const float*)d_in[4];
  const float* lz     = (const float*)d_in[5];
  const float* ly     = (const float*)d_in[6];
  const float* lx     = (const float*)d_in[7];
  const float* W      = (const float*)d_in[8];
  const float* bias   = (const float*)d_in[9];
  float* out = (float*)d_out;
  int n = in_sizes[0] / 3;
  int nwg256 = (n + 255) / 256;
  int nwg32  = (n + 31) / 32;

  const size_t planesU = (size_t)3 * RES * RES * STR;   // padded
  const size_t linesU  = (size_t)3 * RES * STR;
  const size_t wtU     = (size_t)RANK * OUT_CH;
  const size_t histU   = NBKT;
  const size_t topsU   = 64;
  const size_t keyrU   = (size_t)n;
  const size_t sortedU = (size_t)4 * n;
  const size_t stagedU = (size_t)4 * n;
  const size_t needStaged = (planesU + linesU + wtU + histU + topsU + keyrU + sortedU + stagedU) * 4;
  const size_t needFull   = (planesU + linesU + wtU + histU + topsU + keyrU + sortedU) * 4;
  const size_t needMid    = (planesU + linesU + wtU) * 4;

  if (ws_size >= needStaged){
    u32* pl      = (u32*)d_ws;
    u32* ln      = pl + planesU;
    float* wt    = (float*)(ln + linesU);
    u32* hist    = (u32*)(wt + wtU);
    u32* tops    = hist + histU;
    u32* keyrank = tops + topsU;
    float4* sorted = (float4*)(keyrank + keyrU);
    float4* staged = sorted + n;
    zero_hist<<<NBKT / 1024, 1024, 0, stream>>>(hist);
    prep_fused<true><<<TRANS_P + TRANS_L + nwg256, 256, 0, stream>>>(
        pxy, pxz, pyz, lz, ly, lx, W, wt, coords, aabb, pl, ln, hist, keyrank, staged, n);
    scan_blocks<<<NBKT / 1024, 1024, 0, stream>>>(hist, tops);
    scan_tops<<<1, 64, 0, stream>>>(tops);
    key_scatter_staged<<<nwg256, 256, 0, stream>>>(hist, tops, keyrank, staged, sorted, n);
    geo_coop<true><<<nwg32, 256, 0, stream>>>(sorted, nullptr, nullptr, pl, ln, wt, bias, out, n, nwg32);
  } else if (ws_size >= needFull){
    u32* pl      = (u32*)d_ws;
    u32* ln      = pl + planesU;
    float* wt    = (float*)(ln + linesU);
    u32* hist    = (u32*)(wt + wtU);
    u32* tops    = hist + histU;
    u32* keyrank = tops + topsU;
    float4* sorted = (float4*)(keyrank + keyrU);
    zero_hist<<<NBKT / 1024, 1024, 0, stream>>>(hist);
    prep_fused<false><<<TRANS_P + TRANS_L + nwg256, 256, 0, stream>>>(
        pxy, pxz, pyz, lz, ly, lx, W, wt, coords, aabb, pl, ln, hist, keyrank, nullptr, n);
    scan_blocks<<<NBKT / 1024, 1024, 0, stream>>>(hist, tops);
    scan_tops<<<1, 64, 0, stream>>>(tops);
    key_scatter<<<nwg256, 256, 0, stream>>>(coords, aabb, hist, tops, keyrank, sorted, n);
    geo_coop<true><<<nwg32, 256, 0, stream>>>(sorted, nullptr, nullptr, pl, ln, wt, bias, out, n, nwg32);
  } else if (ws_size >= needMid){
    u32* pl = (u32*)d_ws;
    u32* ln = pl + planesU;
    float* wt = (float*)(ln + linesU);
    prep_fused<false><<<TRANS_P + TRANS_L, 256, 0, stream>>>(
        pxy, pxz, pyz, lz, ly, lx, W, wt, coords, aabb, pl, ln, (u32*)pl, (u32*)pl, nullptr, 0);
    geo_coop<false><<<nwg32, 256, 0, stream>>>(nullptr, coords, aabb, pl, ln, wt, bias, out, n, nwg32);
  } else {
    geo_direct<<<nwg256, 256, 0, stream>>>(coords, aabb, pxy, pxz, pyz, lz, ly, lx, W, bias, out, n);
  }
}

// Round 16
// 334.666 us; speedup vs baseline: 2.7065x; 1.3131x over previous
//
#include <hip/hip_runtime.h>
#include <stdint.h>

#define RES 512
#define RANK 48
#define OUT_CH 32
#define KBITS 5
#define NBKT (1 << (3 * KBITS))   // 32768 buckets
#define STR 32                    // padded: 32 u32 (64 bf16 slots) per texel = 128 B = 1 line

typedef unsigned int u32;
typedef unsigned short u16;
typedef u32 u32x4 __attribute__((ext_vector_type(4)));

// ---------- helpers ----------

static __device__ __forceinline__ u16 f2bf(float f){
  u32 u = __float_as_uint(f);
  u32 r = (u + 0x7fffu + ((u >> 16) & 1u)) >> 16;   // RNE, inputs finite
  return (u16)r;
}

static __device__ __forceinline__ void axis_setup(float c, int& o, float& w){
  float f = (c + 1.f) * 255.5f;        // (c+1)*0.5*(RES-1)
  float of = fminf(fmaxf(floorf(f), 0.f), 510.f);
  o = (int)of; w = f - of;
}

static __device__ __forceinline__ void contract(const float* __restrict__ aabb,
                                                float px, float py, float pz,
                                                float& cx, float& cy, float& cz){
  float c0 = (aabb[0] + aabb[3]) * 0.5f;
  float c1 = (aabb[1] + aabb[4]) * 0.5f;
  float c2 = (aabb[2] + aabb[5]) * 0.5f;
  float h0 = fmaxf((aabb[3] - aabb[0]) * 0.5f, 1e-6f);
  float h1 = fmaxf((aabb[4] - aabb[1]) * 0.5f, 1e-6f);
  float h2 = fmaxf((aabb[5] - aabb[2]) * 0.5f, 1e-6f);
  float x0 = (px - c0) / h0;
  float x1 = (py - c1) / h1;
  float x2 = (pz - c2) / h2;
  float linf = fmaxf(fabsf(x0), fmaxf(fabsf(x1), fabsf(x2)));
  float scale = 1.f;
  if (linf > 1.f){ float inv = 1.f / linf; scale = (2.f - inv) * inv; }
  cx = fminf(fmaxf(x0 * scale, -1.f), 1.f);
  cy = fminf(fmaxf(x1 * scale, -1.f), 1.f);
  cz = fminf(fmaxf(x2 * scale, -1.f), 1.f);
}

static __device__ __forceinline__ u32 spread3(u32 x){
  x &= 0x3FF;
  x = (x | (x << 16)) & 0x030000FF;
  x = (x | (x <<  8)) & 0x0300F00F;
  x = (x | (x <<  4)) & 0x030C30C3;
  x = (x | (x <<  2)) & 0x09249249;
  return x;
}

static __device__ __forceinline__ u32 morton_key(float cx, float cy, float cz){
  u32 kx = (u32)fminf(fmaxf((cx + 1.f) * 16.f, 0.f), 31.f);
  u32 ky = (u32)fminf(fmaxf((cy + 1.f) * 16.f, 0.f), 31.f);
  u32 kz = (u32)fminf(fmaxf((cz + 1.f) * 16.f, 0.f), 31.f);
  return spread3(kx) | (spread3(ky) << 1) | (spread3(kz) << 2);   // 15 bits
}

// ---------- zero hist ----------

__global__ void zero_hist(u32* __restrict__ hist)
{
  hist[blockIdx.x * 1024 + threadIdx.x] = 0u;
}

// ---------- fused prep: transpose planes+lines (STR=32 pad) AND hist+keyrank(+staged) ----------

#define TRANS_P 3072
#define TRANS_L 6

template<bool STAGE>
__global__ void prep_fused(const float* __restrict__ pxy, const float* __restrict__ pxz,
                           const float* __restrict__ pyz,
                           const float* __restrict__ lz, const float* __restrict__ ly,
                           const float* __restrict__ lx,
                           const float* __restrict__ coords, const float* __restrict__ aabb,
                           u32* __restrict__ dstP, u32* __restrict__ dstL,
                           u32* __restrict__ hist, u32* __restrict__ keyrank,
                           float4* __restrict__ staged, int n)
{
  __shared__ u32 lds[256 * 25];
  int bid = blockIdx.x;
  int tid = threadIdx.x;
  if (bid < TRANS_P){
    int xh = bid & 1, y = (bid >> 1) & 511, p = bid >> 10;
    const float* src = (p == 0) ? pxy : (p == 1) ? pxz : pyz;
    int x = xh * 256 + tid;
    #pragma unroll
    for (int r2 = 0; r2 < 24; ++r2){
      float f0 = src[((size_t)(2 * r2) * RES + y) * RES + x];
      float f1 = src[((size_t)(2 * r2 + 1) * RES + y) * RES + x];
      lds[tid * 25 + r2] = (u32)f2bf(f0) | ((u32)f2bf(f1) << 16);
    }
    __syncthreads();
    u32* dplane = dstP + (size_t)p * (RES * RES * STR);
    size_t base = ((size_t)y * RES + xh * 256) * STR;
    for (int t = tid; t < 256 * STR; t += 256){
      int tex = t >> 5, r = t & 31;
      dplane[base + t] = (r < 24) ? lds[tex * 25 + r] : 0u;
    }
  } else if (bid < TRANS_P + TRANS_L){
    int g = (bid - TRANS_P) * 256 + tid;
    if (g < 3 * RES){
      int p = g >> 9, i = g & 511;
      const float* src = (p == 0) ? lz : (p == 1) ? ly : lx;
      u32* d = dstL + (size_t)g * STR;
      #pragma unroll
      for (int r2 = 0; r2 < 24; ++r2){
        float f0 = src[(2 * r2) * RES + i];
        float f1 = src[(2 * r2 + 1) * RES + i];
        d[r2] = (u32)f2bf(f0) | ((u32)f2bf(f1) << 16);
      }
      #pragma unroll
      for (int r2 = 24; r2 < STR; ++r2) d[r2] = 0u;
    }
  } else {
    int i = (bid - TRANS_P - TRANS_L) * 256 + tid;
    if (i < n){
      float cx, cy, cz;
      contract(aabb, coords[3*i], coords[3*i+1], coords[3*i+2], cx, cy, cz);
      u32 key = morton_key(cx, cy, cz);
      u32 rank = atomicAdd(hist + key, 1u);
      keyrank[i] = (rank << 15) | key;   // rank < 2^17 (avg ~30/bucket)
      if (STAGE) staged[i] = make_float4(cx, cy, cz, __uint_as_float((u32)i));
    }
  }
}

// ---------- 2-level scan: 32 blocks x 1024 buckets, then tiny top prefix ----------

__global__ void scan_blocks(u32* __restrict__ hist, u32* __restrict__ tops)
{
  __shared__ u32 part[1024];
  int tid = threadIdx.x;
  int idx = blockIdx.x * 1024 + tid;
  u32 v = hist[idx];
  part[tid] = v;
  __syncthreads();
  for (int off = 1; off < 1024; off <<= 1){
    u32 t = 0;
    if (tid >= off) t = part[tid - off];
    __syncthreads();
    part[tid] += t;
    __syncthreads();
  }
  hist[idx] = part[tid] - v;                       // exclusive prefix within chunk
  if (tid == 1023) tops[blockIdx.x] = part[tid];   // chunk total
}

__global__ void scan_tops(u32* __restrict__ tops)
{
  if (threadIdx.x == 0 && blockIdx.x == 0){
    u32 run = 0;
    #pragma unroll
    for (int b = 0; b < NBKT / 1024; b++){ u32 t = tops[b]; tops[b] = run; run += t; }
  }
}

// ---------- scatter (staged): pure permutation, no recompute ----------

__global__ void key_scatter_staged(const u32* __restrict__ hist, const u32* __restrict__ tops,
                                   const u32* __restrict__ keyrank,
                                   const float4* __restrict__ staged, float4* __restrict__ sorted, int n)
{
  int i = blockIdx.x * 256 + threadIdx.x;
  if (i >= n) return;
  u32 kr = keyrank[i];
  u32 key = kr & 0x7FFFu;
  u32 pos = tops[key >> 10] + hist[key] + (kr >> 15);
  sorted[pos] = staged[i];
}

// ---------- scatter (recompute fallback) ----------

__global__ void key_scatter(const float* __restrict__ coords, const float* __restrict__ aabb,
                            const u32* __restrict__ hist, const u32* __restrict__ tops,
                            const u32* __restrict__ keyrank, float4* __restrict__ sorted, int n)
{
  int i = blockIdx.x * 256 + threadIdx.x;
  if (i >= n) return;
  float cx, cy, cz;
  contract(aabb, coords[3*i], coords[3*i+1], coords[3*i+2], cx, cy, cz);
  u32 kr = keyrank[i];
  u32 key = kr & 0x7FFFu;
  u32 pos = tops[key >> 10] + hist[key] + (kr >> 15);
  sorted[pos] = make_float4(cx, cy, cz, __uint_as_float((u32)i));
}

// ---------- cooperative main kernel: 8 lanes per point (R11-exact core, proven 189us) ----------
// Lane k of a group owns ranks 8k..8k+7 (u32s 4k..4k+3 of each 128B texel).
// Gather: every texel = ONE u32x4 instr per group (one cache line).
// Matvec: thread (g,k) computes channels 4k..4k+3 of point g over all 48 ranks.
// NOTE: do NOT raise launch_bounds min-waves (R14: VGPR clamp 48->32 = spill disaster)
// and do NOT remap the matvec threads (R15: 32-distinct-row vmlds reads = bank conflicts).

#define EXLO(u) __uint_as_float((u) << 16)
#define EXHI(u) __uint_as_float((u) & 0xffff0000u)

#define CORN_INIT(ps, taddr, wc) \
  { u32x4 _t = *(const u32x4*)(taddr); \
    _Pragma("unroll") for (int c = 0; c < 4; c++){ \
      ps[2*c] = EXLO(_t[c]) * (wc); ps[2*c+1] = EXHI(_t[c]) * (wc); } }

#define CORN_ACC(ps, taddr, wc) \
  { u32x4 _t = *(const u32x4*)(taddr); \
    _Pragma("unroll") for (int c = 0; c < 4; c++){ \
      ps[2*c] = fmaf(EXLO(_t[c]), (wc), ps[2*c]); ps[2*c+1] = fmaf(EXHI(_t[c]), (wc), ps[2*c+1]); } }

template<bool SORTED>
__global__ __launch_bounds__(256, 2)
void geo_coop(const float4* __restrict__ sorted,
              const float* __restrict__ coords, const float* __restrict__ aabb,
              const u32* __restrict__ pl, const u32* __restrict__ ln,
              const float* __restrict__ W, const float* __restrict__ bias,
              float* __restrict__ out, int n, int nwg)
{
  // Wlds[k][r] = float4 of W channels 4k..4k+3 at rank r; row stride 49 (bank-rotate)
  __shared__ __align__(16) float Wlds[8 * 49 * 4];    // 6272 B
  __shared__ __align__(16) float vmlds[32][68];       // 8704 B (64 data + 4 pad)

  for (int e = threadIdx.x; e < 8 * RANK * 4; e += 256){
    int k = e / (RANK * 4);
    int rem = e - k * (RANK * 4);
    int r = rem >> 2, j = rem & 3;
    Wlds[(k * 49 + r) * 4 + j] = W[(4 * k + j) * RANK + r];
  }
  __syncthreads();

  int bid = blockIdx.x;
  int swz;
  if (SORTED){
    int q = nwg >> 3, r8 = nwg & 7;
    int xcd = bid & 7, sub = bid >> 3;
    swz = (xcd < r8 ? xcd * (q + 1) : r8 * (q + 1) + (xcd - r8) * q) + sub;
  } else {
    swz = bid;
  }

  int g = threadIdx.x >> 3;   // point slot 0..31
  int k = threadIdx.x & 7;    // lane-in-group (rank slice / channel slice)
  int i = swz * 32 + g;
  bool valid = i < n;
  int ic = valid ? i : (n - 1);

  float cx, cy, cz; u32 oidx;
  if (SORTED){
    u32x4 pr = __builtin_nontemporal_load((const u32x4*)(sorted + ic));
    cx = __uint_as_float(pr[0]);
    cy = __uint_as_float(pr[1]);
    cz = __uint_as_float(pr[2]);
    oidx = pr[3];
  } else {
    contract(aabb, coords[3*ic], coords[3*ic+1], coords[3*ic+2], cx, cy, cz);
    oidx = (u32)ic;
  }

  int ox, oy, oz; float wx, wy, wz;
  axis_setup(cx, ox, wx); axis_setup(cy, oy, wy); axis_setup(cz, oz, wz);
  float uxw = 1.f - wx, uyw = 1.f - wy, uzw = 1.f - wz;

  const u32* A   = pl + ((size_t)oy * RES + ox) * STR + 4 * k;                                // plane_xy
  const u32* B   = pl + (size_t)RES * RES * STR     + ((size_t)oz * RES + ox) * STR + 4 * k;  // plane_xz
  const u32* C   = pl + (size_t)2 * RES * RES * STR + ((size_t)oz * RES + oy) * STR + 4 * k;  // plane_yz
  const u32* LZp = ln +                          (size_t)oz * STR + 4 * k;
  const u32* LYp = ln + (size_t)RES * STR     + (size_t)oy * STR + 4 * k;
  const u32* LXp = ln + (size_t)2 * RES * STR + (size_t)ox * STR + 4 * k;

  float vm8[8];
  #pragma unroll
  for (int j = 0; j < 8; j++) vm8[j] = 0.f;

  // plane_xy * line_z
  {
    u32x4 l0 = *(const u32x4*)(LZp);
    u32x4 l1 = *(const u32x4*)(LZp + STR);
    float lv8[8], ps8[8];
    #pragma unroll
    for (int c = 0; c < 4; c++){
      float a0 = EXLO(l0[c]), a1 = EXHI(l0[c]);
      float b0 = EXLO(l1[c]), b1 = EXHI(l1[c]);
      lv8[2*c]   = fmaf(wz, b0 - a0, a0);
      lv8[2*c+1] = fmaf(wz, b1 - a1, a1);
    }
    CORN_INIT(ps8, A,                 uyw * uxw);
    CORN_ACC (ps8, A + STR,           uyw * wx);
    CORN_ACC (ps8, A + RES * STR,     wy * uxw);
    CORN_ACC (ps8, A + RES * STR + STR, wy * wx);
    #pragma unroll
    for (int j = 0; j < 8; j++) vm8[j] = fmaf(ps8[j], lv8[j], vm8[j]);
  }
  // plane_xz * line_y
  {
    u32x4 l0 = *(const u32x4*)(LYp);
    u32x4 l1 = *(const u32x4*)(LYp + STR);
    float lv8[8], ps8[8];
    #pragma unroll
    for (int c = 0; c < 4; c++){
      float a0 = EXLO(l0[c]), a1 = EXHI(l0[c]);
      float b0 = EXLO(l1[c]), b1 = EXHI(l1[c]);
      lv8[2*c]   = fmaf(wy, b0 - a0, a0);
      lv8[2*c+1] = fmaf(wy, b1 - a1, a1);
    }
    CORN_INIT(ps8, B,                 uzw * uxw);
    CORN_ACC (ps8, B + STR,           uzw * wx);
    CORN_ACC (ps8, B + RES * STR,     wz * uxw);
    CORN_ACC (ps8, B + RES * STR + STR, wz * wx);
    #pragma unroll
    for (int j = 0; j < 8; j++) vm8[j] = fmaf(ps8[j], lv8[j], vm8[j]);
  }
  // plane_yz * line_x
  {
    u32x4 l0 = *(const u32x4*)(LXp);
    u32x4 l1 = *(const u32x4*)(LXp + STR);
    float lv8[8], ps8[8];
    #pragma unroll
    for (int c = 0; c < 4; c++){
      float a0 = EXLO(l0[c]), a1 = EXHI(l0[c]);
      float b0 = EXLO(l1[c]), b1 = EXHI(l1[c]);
      lv8[2*c]   = fmaf(wx, b0 - a0, a0);
      lv8[2*c+1] = fmaf(wx, b1 - a1, a1);
    }
    CORN_INIT(ps8, C,                 uzw * uyw);
    CORN_ACC (ps8, C + STR,           uzw * wy);
    CORN_ACC (ps8, C + RES * STR,     wz * uyw);
    CORN_ACC (ps8, C + RES * STR + STR, wz * wy);
    #pragma unroll
    for (int j = 0; j < 8; j++) vm8[j] = fmaf(ps8[j], lv8[j], vm8[j]);
  }

  // hand off vm to LDS (f32, exact)
  *(float4*)&vmlds[g][8 * k]     = make_float4(vm8[0], vm8[1], vm8[2], vm8[3]);
  *(float4*)&vmlds[g][8 * k + 4] = make_float4(vm8[4], vm8[5], vm8[6], vm8[7]);
  __syncthreads();

  // matvec: thread (g,k) -> channels 4k..4k+3 of point g over all 48 ranks
  float vmv[RANK];
  #pragma unroll
  for (int qd = 0; qd < 12; qd++){
    float4 v4 = *(const float4*)&vmlds[g][qd * 4];
    vmv[4*qd+0] = v4.x; vmv[4*qd+1] = v4.y; vmv[4*qd+2] = v4.z; vmv[4*qd+3] = v4.w;
  }
  float4 accv = ((const float4*)bias)[k];
  const float4* wk = (const float4*)(Wlds + (size_t)k * 49 * 4);
  #pragma unroll
  for (int r = 0; r < RANK; r++){
    float4 w4 = wk[r];
    accv.x = fmaf(vmv[r], w4.x, accv.x);
    accv.y = fmaf(vmv[r], w4.y, accv.y);
    accv.z = fmaf(vmv[r], w4.z, accv.z);
    accv.w = fmaf(vmv[r], w4.w, accv.w);
  }

  if (valid){
    *(float4*)(out + (size_t)oidx * 32 + 4 * k) = accv;
  }
}

// ---------- fallback (ws too small): direct sampling from original layout ----------

__global__ __launch_bounds__(256, 2)
void geo_direct(const float* __restrict__ coords, const float* __restrict__ aabb,
                const float* __restrict__ PXY, const float* __restrict__ PXZ, const float* __restrict__ PYZ,
                const float* __restrict__ LZ, const float* __restrict__ LY, const float* __restrict__ LX,
                const float* __restrict__ W, const float* __restrict__ bias,
                float* __restrict__ out, int n)
{
  __shared__ __align__(16) float Wt[RANK * OUT_CH];
  for (int t = threadIdx.x; t < RANK * OUT_CH; t += 256){
    int r = t >> 5, o = t & 31;
    Wt[t] = W[o * RANK + r];
  }
  __syncthreads();

  int i = blockIdx.x * 256 + threadIdx.x;
  if (i >= n) return;

  float cx, cy, cz;
  contract(aabb, coords[3*i], coords[3*i+1], coords[3*i+2], cx, cy, cz);
  int ox, oy, oz; float wx, wy, wz;
  axis_setup(cx, ox, wx); axis_setup(cy, oy, wy); axis_setup(cz, oz, wz);

  int offA = oy * RES + ox, offB = oz * RES + ox, offC = oz * RES + oy;
  float uxw = 1.f - wx, uyw = 1.f - wy, uzw = 1.f - wz;
  float aw00 = uyw*uxw, aw01 = uyw*wx, aw10 = wy*uxw, aw11 = wy*wx;
  float bw00 = uzw*uxw, bw01 = uzw*wx, bw10 = wz*uxw, bw11 = wz*wx;
  float cw00 = uzw*uyw, cw01 = uzw*wy, cw10 = wz*uyw, cw11 = wz*wy;

  float acc[OUT_CH];
  #pragma unroll
  for (int o = 0; o < 8; o++){
    float4 bv = *(const float4*)(bias + o * 4);
    acc[4*o+0] = bv.x; acc[4*o+1] = bv.y; acc[4*o+2] = bv.z; acc[4*o+3] = bv.w;
  }
  const float4* Wt4 = (const float4*)Wt;

  for (int r = 0; r < RANK; r++){
    const float* pA = PXY + (size_t)r * RES * RES;
    const float* pB = PXZ + (size_t)r * RES * RES;
    const float* pC = PYZ + (size_t)r * RES * RES;
    float va = fmaf(pA[offA], aw00, fmaf(pA[offA+1], aw01, fmaf(pA[offA+RES], aw10, pA[offA+RES+1]*aw11)));
    float vb = fmaf(pB[offB], bw00, fmaf(pB[offB+1], bw01, fmaf(pB[offB+RES], bw10, pB[offB+RES+1]*bw11)));
    float vc = fmaf(pC[offC], cw00, fmaf(pC[offC+1], cw01, fmaf(pC[offC+RES], cw10, pC[offC+RES+1]*cw11)));
    float l0;
    l0 = LZ[r * RES + oz];
    float lzv = fmaf(wz, LZ[r * RES + oz + 1] - l0, l0);
    l0 = LY[r * RES + oy];
    float lyv = fmaf(wy, LY[r * RES + oy + 1] - l0, l0);
    l0 = LX[r * RES + ox];
    float lxv = fmaf(wx, LX[r * RES + ox + 1] - l0, l0);
    float vm = fmaf(va, lzv, fmaf(vb, lyv, vc * lxv));
    const float4* wrow = Wt4 + r * 8;
    #pragma unroll
    for (int q = 0; q < 8; q++){
      float4 w4 = wrow[q];
      acc[4*q+0] = fmaf(vm, w4.x, acc[4*q+0]); acc[4*q+1] = fmaf(vm, w4.y, acc[4*q+1]);
      acc[4*q+2] = fmaf(vm, w4.z, acc[4*q+2]); acc[4*q+3] = fmaf(vm, w4.w, acc[4*q+3]);
    }
  }

  float4* o4 = (float4*)(out + (size_t)i * 32);
  #pragma unroll
  for (int q = 0; q < 8; q++)
    o4[q] = make_float4(acc[4*q+0], acc[4*q+1], acc[4*q+2], acc[4*q+3]);
}

// ---------- launch ----------

extern "C" void kernel_launch(void* const* d_in, const int* in_sizes, int n_in,
                              void* d_out, int out_size, void* d_ws, size_t ws_size,
                              hipStream_t stream)
{
  const float* coords = (const float*)d_in[0];
  const float* aabb   = (const float*)d_in[1];
  const float* pxy    = (const float*)d_in[2];
  const float* pxz    = (const float*)d_in[3];
  const float* pyz    = (const float*)d_in[4];
  const float* lz     = (const float*)d_in[5];
  const float* ly     = (const float*)d_in[6];
  const float* lx     = (const float*)d_in[7];
  const float* W      = (const float*)d_in[8];
  const float* bias   = (const float*)d_in[9];
  float* out = (float*)d_out;
  int n = in_sizes[0] / 3;
  int nwg256 = (n + 255) / 256;
  int nwg32  = (n + 31) / 32;

  const size_t planesU = (size_t)3 * RES * RES * STR;   // padded
  const size_t linesU  = (size_t)3 * RES * STR;
  const size_t histU   = NBKT;
  const size_t topsU   = 64;
  const size_t keyrU   = (size_t)n;
  const size_t sortedU = (size_t)4 * n;
  const size_t stagedU = (size_t)4 * n;
  const size_t needStaged = (planesU + linesU + histU + topsU + keyrU + sortedU + stagedU) * 4;
  const size_t needFull   = (planesU + linesU + histU + topsU + keyrU + sortedU) * 4;

  if (ws_size >= needStaged){
    u32* pl      = (u32*)d_ws;
    u32* ln      = pl + planesU;
    u32* hist    = ln + linesU;
    u32* tops    = hist + histU;
    u32* keyrank = tops + topsU;
    float4* sorted = (float4*)(keyrank + keyrU);
    float4* staged = sorted + n;
    zero_hist<<<NBKT / 1024, 1024, 0, stream>>>(hist);
    prep_fused<true><<<TRANS_P + TRANS_L + nwg256, 256, 0, stream>>>(
        pxy, pxz, pyz, lz, ly, lx, coords, aabb, pl, ln, hist, keyrank, staged, n);
    scan_blocks<<<NBKT / 1024, 1024, 0, stream>>>(hist, tops);
    scan_tops<<<1, 64, 0, stream>>>(tops);
    key_scatter_staged<<<nwg256, 256, 0, stream>>>(hist, tops, keyrank, staged, sorted, n);
    geo_coop<true><<<nwg32, 256, 0, stream>>>(sorted, nullptr, nullptr, pl, ln, W, bias, out, n, nwg32);
  } else if (ws_size >= needFull){
    u32* pl      = (u32*)d_ws;
    u32* ln      = pl + planesU;
    u32* hist    = ln + linesU;
    u32* tops    = hist + histU;
    u32* keyrank = tops + topsU;
    float4* sorted = (float4*)(keyrank + keyrU);
    zero_hist<<<NBKT / 1024, 1024, 0, stream>>>(hist);
    prep_fused<false><<<TRANS_P + TRANS_L + nwg256, 256, 0, stream>>>(
        pxy, pxz, pyz, lz, ly, lx, coords, aabb, pl, ln, hist, keyrank, nullptr, n);
    scan_blocks<<<NBKT / 1024, 1024, 0, stream>>>(hist, tops);
    scan_tops<<<1, 64, 0, stream>>>(tops);
    key_scatter<<<nwg256, 256, 0, stream>>>(coords, aabb, hist, tops, keyrank, sorted, n);
    geo_coop<true><<<nwg32, 256, 0, stream>>>(sorted, nullptr, nullptr, pl, ln, W, bias, out, n, nwg32);
  } else if (ws_size >= (planesU + linesU) * 4){
    u32* pl = (u32*)d_ws;
    u32* ln = pl + planesU;
    prep_fused<false><<<TRANS_P + TRANS_L, 256, 0, stream>>>(
        pxy, pxz, pyz, lz, ly, lx, coords, aabb, pl, ln, (u32*)pl, (u32*)pl, nullptr, 0);
    geo_coop<false><<<nwg32, 256, 0, stream>>>(nullptr, coords, aabb, pl, ln, W, bias, out, n, nwg32);
  } else {
    geo_direct<<<nwg256, 256, 0, stream>>>(coords, aabb, pxy, pxz, pyz, lz, ly, lx, W, bias, out, n);
  }
}